// Round 2
// baseline (492.286 us; speedup 1.0000x reference)
//
#include <hip/hip_runtime.h>
#include <stdint.h>
#include <math.h>

// Problem constants (reference file)
#define NROW 8192   // N rows of input
#define KDIM 2048   // F_IN
#define NDIM 2048   // F_OUT
//
// Reference reduces EXACTLY to out = elu(input @ W):
//   scores = where(eye>0, e, -9e15) -> softmax rows one-hot (exp(-9e15)==0 in fp32)
//   attention = I -> h_prime = h.  adj and a are numerically unused.

typedef __attribute__((ext_vector_type(8)))  short bf16x8;   // 8 bf16 = 4 VGPRs
typedef __attribute__((ext_vector_type(16))) float f32x16;   // 32x32 MFMA acc

__device__ __forceinline__ unsigned short f32_to_bf16(float f) {
    union { float f; unsigned int u; } v; v.f = f;
    unsigned int u = v.u;
    unsigned int r = u + 0x7FFFu + ((u >> 16) & 1u);  // RNE
    return (unsigned short)(r >> 16);
}

// Fused prep: blocks [0, 16384) convert input fp32->bf16 (vectorized);
// blocks [16384, 20480) transpose+convert W (KxN fp32) -> Wt (NxK bf16).
#define CVT_BLOCKS (NROW * KDIM / 4 / 256)          // 16384
#define TRN_BLOCKS ((NDIM / 32) * (KDIM / 32))      // 4096

__global__ void prep_kernel(const float* __restrict__ in,
                            unsigned short* __restrict__ Abf,
                            const float* __restrict__ W,
                            unsigned short* __restrict__ Wt) {
    __shared__ float tile[32][33];  // +1 pad: conflict-free transpose
    int tid = threadIdx.x;
    if (blockIdx.x < CVT_BLOCKS) {
        int i = (blockIdx.x * 256 + tid) * 4;
        float4 f = *(const float4*)(in + i);
        ushort4 o;
        o.x = f32_to_bf16(f.x);
        o.y = f32_to_bf16(f.y);
        o.z = f32_to_bf16(f.z);
        o.w = f32_to_bf16(f.w);
        *(ushort4*)(Abf + i) = o;
    } else {
        int b = blockIdx.x - CVT_BLOCKS;
        int x0 = (b & 63) * 32;        // N coord
        int y0 = (b >> 6) * 32;        // K coord
        int tx = tid & 31, ty = tid >> 5;   // (32, 8)
        #pragma unroll
        for (int j = 0; j < 32; j += 8)
            tile[ty + j][tx] = W[(size_t)(y0 + ty + j) * NDIM + x0 + tx];
        __syncthreads();
        #pragma unroll
        for (int j = 0; j < 32; j += 8)
            Wt[(size_t)(x0 + ty + j) * KDIM + y0 + tx] = f32_to_bf16(tile[tx][ty + j]);
    }
}

// ---------------- GEMM: C[M,N] = elu(A[M,K] * Wt[N,K]^T) ----------------
// 128x128 tile, BK=64 (half the barriers of m97's BK=32), 32x32x16 MFMA
// (2382 TF ubench vs 2075 for 16x16x32; 4x fewer issue slots per FLOP).
#define BM 128
#define BN 128
#define BK 64

__device__ __forceinline__ void async_ld16(const unsigned short* g, unsigned short* l) {
    __builtin_amdgcn_global_load_lds(
        (const __attribute__((address_space(1))) void*)g,
        (__attribute__((address_space(3))) void*)l,
        16, 0, 0);
}

__global__ __launch_bounds__(256)
void gemm_bf16_elu(const unsigned short* __restrict__ A,   // M x K bf16
                   const unsigned short* __restrict__ Bt,  // N x K bf16 (= W^T)
                   float* __restrict__ C) {                // M x N fp32
    __shared__ unsigned short As[BM * BK];  // 16 KB, [m][k] k-contiguous
    __shared__ unsigned short Bs[BN * BK];  // 16 KB, [n][k] k-contiguous

    const int tid  = threadIdx.x;
    const int wave = tid >> 6;
    const int lane = tid & 63;
    const int half = lane >> 5;   // 0/1
    const int l32  = lane & 31;

    const int m0 = blockIdx.y * BM;
    const int n0 = blockIdx.x * BN;
    const int wm = (wave >> 1) * 64;   // wave's 64x64 subtile
    const int wn = (wave & 1) * 64;

    // Staging: chunk g in [0,1024): tile-row g>>3, 8-elem slot g&7; LDS off g*16 B.
    // Lanes consecutive in g -> satisfies global_load_lds uniform-base+lane*16.
    const unsigned short* gA[4];
    const unsigned short* gB[4];
    unsigned short* lA[4];
    unsigned short* lB[4];
    #pragma unroll
    for (int c = 0; c < 4; ++c) {
        int g = tid + c * 256;
        gA[c] = A  + (size_t)(m0 + (g >> 3)) * KDIM + (g & 7) * 8;
        gB[c] = Bt + (size_t)(n0 + (g >> 3)) * KDIM + (g & 7) * 8;
        lA[c] = As + g * 8;
        lB[c] = Bs + g * 8;
    }

    f32x16 acc[2][2];
    #pragma unroll
    for (int i = 0; i < 2; ++i)
        #pragma unroll
        for (int j = 0; j < 2; ++j) {
            f32x16 z = {0.f,0.f,0.f,0.f,0.f,0.f,0.f,0.f,
                        0.f,0.f,0.f,0.f,0.f,0.f,0.f,0.f};
            acc[i][j] = z;
        }

    for (int k0 = 0; k0 < KDIM; k0 += BK) {
        #pragma unroll
        for (int c = 0; c < 4; ++c) {
            async_ld16(gA[c] + k0, lA[c]);
            async_ld16(gB[c] + k0, lB[c]);
        }
        __syncthreads();  // vmcnt drained before barrier -> LDS valid for all waves

        // A frag: [m=l32][k=half*8+j] per 16-k step; same pattern for B (n=l32).
        #pragma unroll
        for (int kh = 0; kh < 4; ++kh) {
            bf16x8 af[2], bg[2];
            #pragma unroll
            for (int i = 0; i < 2; ++i)
                af[i] = *(const bf16x8*)(As + (wm + i * 32 + l32) * BK + kh * 16 + half * 8);
            #pragma unroll
            for (int j = 0; j < 2; ++j)
                bg[j] = *(const bf16x8*)(Bs + (wn + j * 32 + l32) * BK + kh * 16 + half * 8);
            #pragma unroll
            for (int i = 0; i < 2; ++i)
                #pragma unroll
                for (int j = 0; j < 2; ++j)
                    acc[i][j] = __builtin_amdgcn_mfma_f32_32x32x16_bf16(
                        af[i], bg[j], acc[i][j], 0, 0, 0);
        }
        __syncthreads();  // all LDS reads done before next iter's loads land
    }

    // Epilogue: C/D layout (m74/m101): col=lane&31, row=(reg&3)+8*(reg>>2)+4*(lane>>5)
    #pragma unroll
    for (int i = 0; i < 2; ++i)
        #pragma unroll
        for (int j = 0; j < 2; ++j)
            #pragma unroll
            for (int r = 0; r < 16; ++r) {
                int row = (r & 3) + 8 * (r >> 2) + 4 * half;
                int m = m0 + wm + i * 32 + row;
                int col = n0 + wn + j * 32 + l32;
                float v = acc[i][j][r];
                C[(size_t)m * NDIM + col] = (v > 0.f) ? v : (__expf(v) - 1.f);
            }
}

extern "C" void kernel_launch(void* const* d_in, const int* in_sizes, int n_in,
                              void* d_out, int out_size, void* d_ws, size_t ws_size,
                              hipStream_t stream) {
    const float* input = (const float*)d_in[0];
    // d_in[1] = adj : numerically unused (attention == I exactly)
    const float* W     = (const float*)d_in[2];
    // d_in[3] = a   : numerically unused
    float* out = (float*)d_out;

    // Workspace: A_bf16 (33.5 MB) then Wt_bf16 (8.4 MB)
    unsigned short* Abf = (unsigned short*)d_ws;
    unsigned short* Wt  = Abf + (size_t)NROW * KDIM;

    prep_kernel<<<CVT_BLOCKS + TRN_BLOCKS, 256, 0, stream>>>(input, Abf, W, Wt);
    gemm_bf16_elu<<<dim3(NDIM / BN, NROW / BM), 256, 0, stream>>>(Abf, Wt, out);
}

// Round 3
// 438.356 us; speedup vs baseline: 1.1230x; 1.1230x over previous
//
#include <hip/hip_runtime.h>
#include <stdint.h>
#include <math.h>

// Problem constants (reference file)
#define NROW 8192   // N rows of input
#define KDIM 2048   // F_IN
#define NDIM 2048   // F_OUT
//
// Reference reduces EXACTLY to out = elu(input @ W):
//   scores = where(eye>0, e, -9e15) -> softmax rows one-hot (exp(-9e15)==0 in fp32)
//   attention = I -> h_prime = h.  adj and a are numerically unused.

typedef __attribute__((ext_vector_type(8)))  short bf16x8;   // 8 bf16 = 4 VGPRs
typedef __attribute__((ext_vector_type(16))) float f32x16;   // 32x32 MFMA acc

__device__ __forceinline__ unsigned short f32_to_bf16(float f) {
    union { float f; unsigned int u; } v; v.f = f;
    unsigned int u = v.u;
    unsigned int r = u + 0x7FFFu + ((u >> 16) & 1u);  // RNE
    return (unsigned short)(r >> 16);
}

// Fused prep: blocks [0, 16384) convert input fp32->bf16 (vectorized);
// blocks [16384, 20480) transpose+convert W (KxN fp32) -> Wt (NxK bf16).
#define CVT_BLOCKS (NROW * KDIM / 4 / 256)          // 16384
#define TRN_BLOCKS ((NDIM / 32) * (KDIM / 32))      // 4096

__global__ void prep_kernel(const float* __restrict__ in,
                            unsigned short* __restrict__ Abf,
                            const float* __restrict__ W,
                            unsigned short* __restrict__ Wt) {
    __shared__ float tile[32][33];  // +1 pad: conflict-free transpose
    int tid = threadIdx.x;
    if (blockIdx.x < CVT_BLOCKS) {
        int i = (blockIdx.x * 256 + tid) * 4;
        float4 f = *(const float4*)(in + i);
        ushort4 o;
        o.x = f32_to_bf16(f.x);
        o.y = f32_to_bf16(f.y);
        o.z = f32_to_bf16(f.z);
        o.w = f32_to_bf16(f.w);
        *(ushort4*)(Abf + i) = o;
    } else {
        int b = blockIdx.x - CVT_BLOCKS;
        int x0 = (b & 63) * 32;        // N coord
        int y0 = (b >> 6) * 32;        // K coord
        int tx = tid & 31, ty = tid >> 5;   // (32, 8)
        #pragma unroll
        for (int j = 0; j < 32; j += 8)
            tile[ty + j][tx] = W[(size_t)(y0 + ty + j) * NDIM + x0 + tx];
        __syncthreads();
        #pragma unroll
        for (int j = 0; j < 32; j += 8)
            Wt[(size_t)(x0 + ty + j) * KDIM + y0 + tx] = f32_to_bf16(tile[tx][ty + j]);
    }
}

// ---------------- GEMM: C[M,N] = elu(A[M,K] * Wt[N,K]^T) ----------------
// 128x128 tile, BK=64 (half the barriers of BK=32), 32x32x16 MFMA.
// Round-2 lesson: BK=64 row stride = 128 B = 0 mod 32 banks -> fragment
// ds_read_b128 was a 32-lanes-on-8-banks conflict (4x LDS cost). Fix: XOR
// source-chunk swizzle — LDS slot (row, slot) holds global chunk
// (row, slot ^ (row&7)); fragment reads then sweep all 8 bank groups.
#define BM 128
#define BN 128
#define BK 64

__device__ __forceinline__ void async_ld16(const unsigned short* g, unsigned short* l) {
    __builtin_amdgcn_global_load_lds(
        (const __attribute__((address_space(1))) void*)g,
        (__attribute__((address_space(3))) void*)l,
        16, 0, 0);
}

__global__ __launch_bounds__(256)
void gemm_bf16_elu(const unsigned short* __restrict__ A,   // M x K bf16
                   const unsigned short* __restrict__ Bt,  // N x K bf16 (= W^T)
                   float* __restrict__ C) {                // M x N fp32
    __shared__ unsigned short As[BM * BK];  // 16 KB, [m][k-swizzled]
    __shared__ unsigned short Bs[BN * BK];  // 16 KB, [n][k-swizzled]

    const int tid  = threadIdx.x;
    const int wave = tid >> 6;
    const int lane = tid & 63;
    const int half = lane >> 5;   // 0/1
    const int l32  = lane & 31;
    const int rx   = l32 & 7;     // row&7 for this lane's fragment rows

    const int m0 = blockIdx.y * BM;
    const int n0 = blockIdx.x * BN;
    const int wm = (wave >> 1) * 64;   // wave's 64x64 subtile
    const int wn = (wave & 1) * 64;

    // Staging with XOR swizzle: chunk g in [0,1024): row g>>3, slot g&7;
    // lane g fetches global k-slot (g&7)^(row&7) into LDS byte g*16.
    // Coalescing intact: each 8-lane group still covers its row's 128 B.
    const unsigned short* gA[4];
    const unsigned short* gB[4];
    unsigned short* lA[4];
    unsigned short* lB[4];
    #pragma unroll
    for (int c = 0; c < 4; ++c) {
        int g = tid + c * 256;
        int row = g >> 3;
        int sslot = (g & 7) ^ (row & 7);
        gA[c] = A  + (size_t)(m0 + row) * KDIM + sslot * 8;
        gB[c] = Bt + (size_t)(n0 + row) * KDIM + sslot * 8;
        lA[c] = As + g * 8;
        lB[c] = Bs + g * 8;
    }

    f32x16 acc[2][2];
    #pragma unroll
    for (int i = 0; i < 2; ++i)
        #pragma unroll
        for (int j = 0; j < 2; ++j) {
            f32x16 z = {0.f,0.f,0.f,0.f,0.f,0.f,0.f,0.f,
                        0.f,0.f,0.f,0.f,0.f,0.f,0.f,0.f};
            acc[i][j] = z;
        }

    for (int k0 = 0; k0 < KDIM; k0 += BK) {
        #pragma unroll
        for (int c = 0; c < 4; ++c) {
            async_ld16(gA[c] + k0, lA[c]);
            async_ld16(gB[c] + k0, lB[c]);
        }
        __syncthreads();  // vmcnt drained before barrier -> LDS valid for all waves

        // Fragment for (row, kslot = kh*2+half): LDS slot = kslot ^ (row&7).
        // row = wm + i*32 + l32 -> row&7 == l32&7 == rx.
        #pragma unroll
        for (int kh = 0; kh < 4; ++kh) {
            const int ks = ((kh * 2 + half) ^ rx) * 8;
            bf16x8 af[2], bg[2];
            #pragma unroll
            for (int i = 0; i < 2; ++i)
                af[i] = *(const bf16x8*)(As + (wm + i * 32 + l32) * BK + ks);
            #pragma unroll
            for (int j = 0; j < 2; ++j)
                bg[j] = *(const bf16x8*)(Bs + (wn + j * 32 + l32) * BK + ks);
            #pragma unroll
            for (int i = 0; i < 2; ++i)
                #pragma unroll
                for (int j = 0; j < 2; ++j)
                    acc[i][j] = __builtin_amdgcn_mfma_f32_32x32x16_bf16(
                        af[i], bg[j], acc[i][j], 0, 0, 0);
        }
        __syncthreads();  // all LDS reads done before next iter's loads land
    }

    // Epilogue: C/D layout (m74/m101): col=lane&31, row=(reg&3)+8*(reg>>2)+4*(lane>>5)
    #pragma unroll
    for (int i = 0; i < 2; ++i)
        #pragma unroll
        for (int j = 0; j < 2; ++j)
            #pragma unroll
            for (int r = 0; r < 16; ++r) {
                int row = (r & 3) + 8 * (r >> 2) + 4 * half;
                int m = m0 + wm + i * 32 + row;
                int col = n0 + wn + j * 32 + l32;
                float v = acc[i][j][r];
                C[(size_t)m * NDIM + col] = (v > 0.f) ? v : (__expf(v) - 1.f);
            }
}

extern "C" void kernel_launch(void* const* d_in, const int* in_sizes, int n_in,
                              void* d_out, int out_size, void* d_ws, size_t ws_size,
                              hipStream_t stream) {
    const float* input = (const float*)d_in[0];
    // d_in[1] = adj : numerically unused (attention == I exactly)
    const float* W     = (const float*)d_in[2];
    // d_in[3] = a   : numerically unused
    float* out = (float*)d_out;

    // Workspace: A_bf16 (33.5 MB) then Wt_bf16 (8.4 MB)
    unsigned short* Abf = (unsigned short*)d_ws;
    unsigned short* Wt  = Abf + (size_t)NROW * KDIM;

    prep_kernel<<<CVT_BLOCKS + TRN_BLOCKS, 256, 0, stream>>>(input, Abf, W, Wt);
    gemm_bf16_elu<<<dim3(NDIM / BN, NROW / BM), 256, 0, stream>>>(Abf, Wt, out);
}